// Round 20
// baseline (105.154 us; speedup 1.0000x reference)
//
#include <hip/hip_runtime.h>
#include <hip/hip_fp16.h>

#define TEX_H 256
#define TEX_W 256
#define FCH 16
#define NPIX (8 * 256 * 256)
#define NCELL (256 * 256)
#define NBLKA 1024            // pass-A blocks, 512 pixels each
#define NSLAB 64              // slab = 4 texture rows = 1024 cells
#define SLABCELLS 1024
#define HALFCELLS 512
#define BCAP 20               // entries per bucket (lambda=8; P(ovf)~1e-4/bucket)
#define BSTRIDE 24            // bucket stride in words (96 B)

#define SQRT2_F 1.41421356237f
#define W_EDGE   0.24311673443f   // exp(-sqrt(2))
#define W_DIAG   0.13533528324f   // exp(-2)

typedef float vf4 __attribute__((ext_vector_type(4)));

// ws layout (bytes), total 8,790,016 <= 9,052,160 proven available (r12):
//  entries [NBLKA][NSLAB][24] u32 @ 0         (6,291,456)  word0=count, 1..20=entries
//  halo    [NCELL][8] __half2    @ 6,291,456  (2,097,152)  fp16 channel sums
//  hcnt    [NCELL] f32           @ 8,388,608  (  262,144)
//  dirc    [2048][16] f32        @ 8,650,752  (  131,072)  boundary strips
//  dirw    [2048] f32            @ 8,781,824  (    8,192)
#define ENT_OFF_B  0
#define HALO_OFF_B (NBLKA * NSLAB * BSTRIDE * 4)
#define HCNT_OFF_B (HALO_OFF_B + NCELL * 32)
#define DIRC_OFF_B (HCNT_OFF_B + NCELL * 4)
#define DIRW_OFF_B (DIRC_OFF_B + 2048 * 64)
#define WS_END_B   (DIRW_OFF_B + 2048 * 4)

// exact reference boundary path (u<2 or v<2), scalar
__device__ __forceinline__ void boundary_splat16(float u, float v, int pix,
                                                 const float* __restrict__ f_map,
                                                 float* __restrict__ dirc,
                                                 float* __restrict__ dirw) {
    float fv[16];
    #pragma unroll
    for (int i = 0; i < 4; ++i) {
        vf4 x = *(const vf4*)(f_map + (size_t)pix * FCH + i * 4);
        fv[i*4+0]=x.x; fv[i*4+1]=x.y; fv[i*4+2]=x.z; fv[i*4+3]=x.w;
    }
    float us = fmaxf(u - 2.0f, 0.0f);
    float vs = fmaxf(v - 2.0f, 0.0f);
    for (int kv = 0; kv < 4; ++kv) {
        float vg = vs + (float)kv;
        int vi = (int)vg;
        float dvf = fabsf(vg - v);
        for (int ku = 0; ku < 4; ++ku) {
            float ug = us + (float)ku;
            int ui = (int)ug;
            float duf = fabsf(ug - u);
            float w = expf(-sqrtf(duf * duf + dvf * dvf) * SQRT2_F);
            if (w > 0.1f && vi < TEX_H && ui < TEX_W) {
                int cell = (ui < 4) ? (ui * 256 + vi)        // region 0 (u<2)
                                    : ((4 + vi) * 256 + ui); // region 1 (vi<4)
                float* p = dirc + (size_t)cell * FCH;
                #pragma unroll
                for (int i = 0; i < 16; ++i) unsafeAtomicAdd(p + i, w * fv[i]);
                unsafeAtomicAdd(dirw + cell, w);
            }
        }
    }
}

// rare overflow: direct fp16 pk-atomic accumulation into halo (r15 semantics)
__device__ __forceinline__ void overflow_splat(int pix, int cell,
                                               const float* __restrict__ f_map,
                                               __half2* __restrict__ halo,
                                               float* __restrict__ hcnt) {
    #pragma unroll
    for (int j = 0; j < 8; ++j) {
        float2 fp = ((const float2*)f_map)[(size_t)pix * 8 + j];
        unsafeAtomicAdd(&halo[(size_t)cell * 8 + j], __floats2half2_rn(fp.x, fp.y));
    }
    unsafeAtomicAdd(&hcnt[cell], 1.0f);
}

// ---- pass A: 1024 blocks x 512 pixels (2/thread). LDS histogram over 64
// slabs; interior pixels claim an LDS slot and plain-store a packed entry
// (cell_local<<19 | pix) into the block's contiguous bucket region. NO global
// atomics on the hot path -> no random-RMW wall. ----
__global__ __launch_bounds__(256) void bin2_kernel(
    const float*  __restrict__ f_map,
    const float2* __restrict__ uv_map,
    const float*  __restrict__ mask,
    char* __restrict__ wsb)
{
    __shared__ int s_hist[NSLAB];
    int t = threadIdx.x;
    if (t < NSLAB) s_hist[t] = 0;
    __syncthreads();

    unsigned* ent = (unsigned*)(wsb + ENT_OFF_B) + (size_t)blockIdx.x * NSLAB * BSTRIDE;
    __half2*  halo = (__half2*)(wsb + HALO_OFF_B);
    float*    hcnt = (float*)  (wsb + HCNT_OFF_B);
    float*    dirc = (float*)  (wsb + DIRC_OFF_B);
    float*    dirw = (float*)  (wsb + DIRW_OFF_B);

    #pragma unroll
    for (int k = 0; k < 2; ++k) {
        int pix = blockIdx.x * 512 + k * 256 + t;
        if (mask[pix] != 0.0f) {
            float2 uv = uv_map[pix];
            float u = uv.x * 256.0f;
            float v = uv.y * 256.0f;
            if (u >= 2.0f && v >= 2.0f) {
                int iu = (int)u, iv = (int)v;        // uv<1 => <=255
                int slab = iv >> 2;
                int cl   = ((iv & 3) << 8) | iu;     // cell within slab, 10 bits
                int slot = atomicAdd(&s_hist[slab], 1);   // LDS atomic
                if (slot < BCAP)
                    ent[slab * BSTRIDE + 1 + slot] = ((unsigned)cl << 19) | (unsigned)pix;
                else
                    overflow_splat(pix, iv * 256 + iu, f_map, halo, hcnt);
            } else {
                boundary_splat16(u, v, pix, f_map, dirc, dirw);
            }
        }
    }
    __syncthreads();
    if (t < NSLAB) ent[t * BSTRIDE] = (unsigned)min(s_hist[t], BCAP);
}

// ---- pass B: 256 WGs = (slab 0..63, half 0..1, range 0..1) x 512 threads =
// 32 groups of 16 channel-lanes. Each WG owns a HALF-slab (512 cells, 34 KB
// LDS <= 64 KB limit) and filters entries by the half bit. The 258k random
// f_map READS are 4-deep pipelined (reads ~1.8 TB/s, unlike RMWs). Merge =
// sequential coalesced pk-fp16 atomic streams. ----
__global__ __launch_bounds__(512) void accum_kernel(
    const float* __restrict__ f_map,
    char* __restrict__ wsb)
{
    __shared__ float s_halo[HALFCELLS][FCH];   // 32 KB
    __shared__ float s_cnt[HALFCELLS];         // 2 KB

    for (int i = threadIdx.x; i < HALFCELLS * FCH; i += 512) ((float*)s_halo)[i] = 0.0f;
    for (int i = threadIdx.x; i < HALFCELLS;       i += 512) s_cnt[i] = 0.0f;
    __syncthreads();

    int slab = blockIdx.x >> 2;          // 0..63
    int h    = (blockIdx.x >> 1) & 1;    // half-slab (rows 0-1 vs 2-3)
    int q    = blockIdx.x & 1;           // block range (512 each)
    int g = threadIdx.x >> 4;            // 0..31
    int c = threadIdx.x & 15;

    const unsigned* entbase = (const unsigned*)(wsb + ENT_OFF_B);

    for (int b = q * 512 + g; b < (q + 1) * 512; b += 32) {
        const unsigned* buck = entbase + ((size_t)b * NSLAB + slab) * BSTRIDE;
        unsigned wA = buck[c];                         // words 0..15
        unsigned wB = (c < 8) ? buck[16 + c] : 0u;     // words 16..23
        int count = (int)__shfl(wA, 0, 16);            // word0 = count (<=20)

        for (int e = 1; e <= count; e += 4) {
            int e1 = min(e + 1, count), e2 = min(e + 2, count), e3 = min(e + 3, count);
            unsigned x0 = (e  < 16) ? __shfl(wA, e,  16) : __shfl(wB, e  - 16, 16);
            unsigned x1 = (e1 < 16) ? __shfl(wA, e1, 16) : __shfl(wB, e1 - 16, 16);
            unsigned x2 = (e2 < 16) ? __shfl(wA, e2, 16) : __shfl(wB, e2 - 16, 16);
            unsigned x3 = (e3 < 16) ? __shfl(wA, e3, 16) : __shfl(wB, e3 - 16, 16);
            // half-filter: entry belongs to this WG iff bit9 of cell == h
            bool v0 = ((x0 >> 28) & 1) == (unsigned)h;
            bool v1 = (e + 1 <= count) && (((x1 >> 28) & 1) == (unsigned)h);
            bool v2 = (e + 2 <= count) && (((x2 >> 28) & 1) == (unsigned)h);
            bool v3 = (e + 3 <= count) && (((x3 >> 28) & 1) == (unsigned)h);
            float f0 = v0 ? f_map[(size_t)(x0 & 0x7FFFFu) * FCH + c] : 0.0f;
            float f1 = v1 ? f_map[(size_t)(x1 & 0x7FFFFu) * FCH + c] : 0.0f;
            float f2 = v2 ? f_map[(size_t)(x2 & 0x7FFFFu) * FCH + c] : 0.0f;
            float f3 = v3 ? f_map[(size_t)(x3 & 0x7FFFFu) * FCH + c] : 0.0f;
            if (v0) atomicAdd(&s_halo[(x0 >> 19) & 511][c], f0);
            if (v1) atomicAdd(&s_halo[(x1 >> 19) & 511][c], f1);
            if (v2) atomicAdd(&s_halo[(x2 >> 19) & 511][c], f2);
            if (v3) atomicAdd(&s_halo[(x3 >> 19) & 511][c], f3);
            if (c == 0) {
                if (v0) atomicAdd(&s_cnt[(x0 >> 19) & 511], 1.0f);
                if (v1) atomicAdd(&s_cnt[(x1 >> 19) & 511], 1.0f);
                if (v2) atomicAdd(&s_cnt[(x2 >> 19) & 511], 1.0f);
                if (v3) atomicAdd(&s_cnt[(x3 >> 19) & 511], 1.0f);
            }
        }
    }
    __syncthreads();

    // merge: sequential, fully coalesced pk-fp16 atomic streams
    __half2* halo = (__half2*)(wsb + HALO_OFF_B);
    float*   hcnt = (float*)  (wsb + HCNT_OFF_B);
    size_t cbase = (size_t)slab * SLABCELLS + (size_t)h * HALFCELLS;
    for (int i = threadIdx.x; i < HALFCELLS * 8; i += 512) {
        int cell = i >> 3, wp = i & 7;
        float a = s_halo[cell][wp * 2], bb = s_halo[cell][wp * 2 + 1];
        unsafeAtomicAdd(&halo[(cbase + cell) * 8 + wp], __floats2half2_rn(a, bb));
    }
    for (int i = threadIdx.x; i < HALFCELLS; i += 512) {
        float n = s_cnt[i];
        if (n != 0.0f) unsafeAtomicAdd(&hcnt[cbase + i], n);
    }
}

// ---- finalize: r15's proven kernel (13us, absmax 0.0078). Stage 10x10 halo
// into LDS, 3x3 const-weight conv, merge exact fp32 strips, normalize,
// NT-store the 8 broadcast copies. ----
__global__ __launch_bounds__(256) void finalize_kernel(
    const char* __restrict__ wsb,
    float* __restrict__ out)
{
    const __half2* halo = (const __half2*)(wsb + HALO_OFF_B);
    const float*   hcnt = (const float*)  (wsb + HCNT_OFF_B);
    const float*   dirc = (const float*)  (wsb + DIRC_OFF_B);
    const float*   dirw = (const float*)  (wsb + DIRW_OFF_B);

    __shared__ __half2 s_h[100][8];   // 10x10 cells x 16 ch (fp16)
    __shared__ float   s_n[100];

    int tile = blockIdx.x;                  // 32x32 tiles of 8x8
    int r0 = (tile >> 5) << 3;
    int c0 = (tile & 31) << 3;

    int i = threadIdx.x;
    if (i < 200) {
        int cellIdx = i >> 1, part = i & 1;
        int hr = cellIdx / 10, hc = cellIdx - hr * 10;
        int gr = r0 + hr - 1, gc = c0 + hc - 1;
        uint4 val = make_uint4(0, 0, 0, 0);
        bool inb = (gr >= 0) & (gr < 256) & (gc >= 0) & (gc < 256);
        size_t gcell = inb ? ((size_t)gr * 256 + gc) : 0;
        if (inb)
            val = *(const uint4*)(halo + gcell * 8 + part * 4);
        *(uint4*)&s_h[cellIdx][part * 4] = val;
        if (part == 0) s_n[cellIdx] = inb ? hcnt[gcell] : 0.0f;
    }
    __syncthreads();

    int tx = threadIdx.x >> 2;
    int c4 = threadIdx.x & 3;
    int lr = tx >> 3, lc = tx & 7;
    int gr = r0 + lr, gc = c0 + lc;

    vf4 cs = {0.f, 0.f, 0.f, 0.f};
    float wsm = 0.0f;

    #pragma unroll
    for (int a = 0; a < 3; ++a) {
        #pragma unroll
        for (int b = 0; b < 3; ++b) {
            float w = (a == 1 && b == 1) ? 1.0f
                    : ((a == 1 || b == 1) ? W_EDGE : W_DIAG);
            int idx = (lr + a) * 10 + (lc + b);
            float2 f0 = __half22float2(s_h[idx][c4 * 2 + 0]);
            float2 f1 = __half22float2(s_h[idx][c4 * 2 + 1]);
            cs.x += w * f0.x; cs.y += w * f0.y;
            cs.z += w * f1.x; cs.w += w * f1.y;
            wsm  += w * s_n[idx];
        }
    }

    if (gc < 4) {
        int cell = gc * 256 + gr;
        cs += *(const vf4*)&dirc[(size_t)cell * FCH + c4 * 4];
        wsm += dirw[cell];
    } else if (gr < 4) {
        int cell = (4 + gr) * 256 + gc;
        cs += *(const vf4*)&dirc[(size_t)cell * FCH + c4 * 4];
        wsm += dirw[cell];
    }

    float s = (wsm > 0.01f) ? (1.0f / (wsm + 0.001f)) : 0.0f;
    cs *= s;

    size_t base = ((size_t)gr * 256 + gc) * FCH + c4 * 4;
    #pragma unroll
    for (int b = 0; b < 8; ++b) {
        __builtin_nontemporal_store(cs, (vf4*)&out[(size_t)b * (256 * 256 * FCH) + base]);
    }
}

extern "C" void kernel_launch(void* const* d_in, const int* in_sizes, int n_in,
                              void* d_out, int out_size, void* d_ws, size_t ws_size,
                              hipStream_t stream) {
    const float*  f_map  = (const float*)d_in[0];
    const float2* uv_map = (const float2*)d_in[1];
    const float*  mask   = (const float*)d_in[2];
    float* out = (float*)d_out;
    char*  wsb = (char*)d_ws;

    // zero halo + hcnt + strips (entries' counts are written unconditionally)
    (void)hipMemsetAsync(wsb + HALO_OFF_B, 0, (size_t)(WS_END_B - HALO_OFF_B), stream);

    bin2_kernel<<<NBLKA, 256, 0, stream>>>(f_map, uv_map, mask, wsb);
    accum_kernel<<<NSLAB * 2 * 2, 512, 0, stream>>>(f_map, wsb);
    finalize_kernel<<<1024, 256, 0, stream>>>(wsb, out);
}

// Round 23
// 71.388 us; speedup vs baseline: 1.4730x; 1.4730x over previous
//
#include <hip/hip_runtime.h>
#include <hip/hip_fp16.h>

#define TEX_H 256
#define TEX_W 256
#define FCH 16
#define NPIX (8 * 256 * 256)
#define NCELL (256 * 256)

#define SQRT2_F 1.41421356237f
#define W_EDGE   0.24311673443f   // exp(-sqrt(2))
#define W_DIAG   0.13533528324f   // exp(-2)

typedef float vf4 __attribute__((ext_vector_type(4)));

// physical XCD id (HW-verified readable on MI355X: learn_hip m09).
// Value clamped to 0..7; correctness does NOT depend on what this returns.
__device__ __forceinline__ int xcc_id() {
    unsigned x;
    asm volatile("s_getreg_b32 %0, hwreg(HW_REG_XCC_ID)" : "=s"(x));
    return (int)(x & 7);
}

// ---- splat: r15 structure (8 lanes/pixel, one pk-fp16 atomic per lane +
// count on lane 0) but into the replica owned by this wave's PHYSICAL XCD.
// With nrepl=8 each halo line is touched by exactly one XCD's L2 -> the RMW
// needs no cross-XCD migration (the mechanism under test). ----
__global__ __launch_bounds__(256) void splat_kernel(
    const float*  __restrict__ f_map,
    const float2* __restrict__ uv_map,
    const float*  __restrict__ mask,
    __half2* __restrict__ halo,      // [nrepl][NCELL][8] half2
    float*   __restrict__ hcnt,      // [nrepl][NCELL]
    float*   __restrict__ dirc,      // [2048][16]
    float*   __restrict__ dirw,      // [2048]
    int shift)                       // rep = xcc >> shift
{
    int tid = blockIdx.x * 256 + threadIdx.x;
    int pix = tid >> 3;
    int l   = tid & 7;

    if (mask[pix] == 0.0f) return;

    float2 uv = uv_map[pix];
    float u = uv.x * 256.0f;
    float v = uv.y * 256.0f;

    if (u >= 2.0f && v >= 2.0f) {
        int rep = xcc_id() >> shift;
        size_t cell = (size_t)rep * NCELL + ((int)v) * 256 + (int)u;
        float2 fp = ((const float2*)f_map)[(size_t)pix * 8 + l]; // ch 2l,2l+1
        unsafeAtomicAdd(&halo[cell * 8 + l], __floats2half2_rn(fp.x, fp.y));
        if (l == 0) unsafeAtomicAdd(&hcnt[cell], 1.0f);
    } else {
        // Exact reference path; passing slots have ui<4 (u<2) or vi<4 (v<2).
        float fa = f_map[(size_t)pix * FCH + l];
        float fb = f_map[(size_t)pix * FCH + l + 8];
        float us = fmaxf(u - 2.0f, 0.0f);
        float vs = fmaxf(v - 2.0f, 0.0f);
        #pragma unroll
        for (int kv = 0; kv < 4; ++kv) {
            float vg = vs + (float)kv;
            int vi = (int)vg;
            float dvf = fabsf(vg - v);
            #pragma unroll
            for (int ku = 0; ku < 4; ++ku) {
                float ug = us + (float)ku;
                int ui = (int)ug;
                float duf = fabsf(ug - u);
                float w = expf(-sqrtf(duf * duf + dvf * dvf) * SQRT2_F);
                if (w > 0.1f && vi < TEX_H && ui < TEX_W) {
                    int cell = (ui < 4) ? (ui * 256 + vi)        // region 0 (u<2)
                                        : ((4 + vi) * 256 + ui); // region 1 (vi<4)
                    unsafeAtomicAdd(&dirc[(size_t)cell * FCH + l],     w * fa);
                    unsafeAtomicAdd(&dirc[(size_t)cell * FCH + l + 8], w * fb);
                    if (l == 0) unsafeAtomicAdd(&dirw[cell], w);
                }
            }
        }
    }
}

// ---- finalize: stage 10x10 halo summed over replicas into LDS (fp32),
// 3x3 const-weight conv, merge exact fp32 strips, normalize, NT-store the
// 8 broadcast copies. (r17's replica-sum staging, r15's conv core.) ----
__global__ __launch_bounds__(256) void finalize_kernel(
    const __half2* __restrict__ halo,
    const float*   __restrict__ hcnt,
    const float*   __restrict__ dirc,
    const float*   __restrict__ dirw,
    int nrepl,
    float* __restrict__ out)
{
    __shared__ float s_h[100][16];    // 10x10 cells x 16 ch fp32
    __shared__ float s_n[100];

    int tile = blockIdx.x;                  // 32x32 tiles of 8x8
    int r0 = (tile >> 5) << 3;
    int c0 = (tile & 31) << 3;

    int i = threadIdx.x;
    if (i < 200) {                          // 2 threads per halo cell
        int cellIdx = i >> 1, part = i & 1;
        int hr = cellIdx / 10, hc = cellIdx - hr * 10;
        int gr = r0 + hr - 1, gc = c0 + hc - 1;
        bool inb = (gr >= 0) & (gr < 256) & (gc >= 0) & (gc < 256);
        float acc[8] = {0,0,0,0,0,0,0,0};
        float ncc = 0.0f;
        if (inb) {
            size_t gcell = (size_t)gr * 256 + gc;
            for (int r = 0; r < nrepl; ++r) {
                uint4 val = *(const uint4*)&halo[((size_t)r * NCELL + gcell) * 8 + part * 4];
                const __half2* hp = (const __half2*)&val;
                #pragma unroll
                for (int j = 0; j < 4; ++j) {
                    float2 f = __half22float2(hp[j]);
                    acc[j * 2 + 0] += f.x;
                    acc[j * 2 + 1] += f.y;
                }
                if (part == 0) ncc += hcnt[(size_t)r * NCELL + gcell];
            }
        }
        #pragma unroll
        for (int j = 0; j < 8; ++j) s_h[cellIdx][part * 8 + j] = acc[j];
        if (part == 0) s_n[cellIdx] = ncc;
    }
    __syncthreads();

    int tx = threadIdx.x >> 2;              // texel 0..63
    int c4 = threadIdx.x & 3;               // float4 chunk 0..3
    int lr = tx >> 3, lc = tx & 7;
    int gr = r0 + lr, gc = c0 + lc;

    vf4 cs = {0.f, 0.f, 0.f, 0.f};
    float wsm = 0.0f;

    #pragma unroll
    for (int a = 0; a < 3; ++a) {
        #pragma unroll
        for (int b = 0; b < 3; ++b) {
            float w = (a == 1 && b == 1) ? 1.0f
                    : ((a == 1 || b == 1) ? W_EDGE : W_DIAG);
            int idx = (lr + a) * 10 + (lc + b);
            cs += w * *(const vf4*)&s_h[idx][c4 * 4];
            wsm += w * s_n[idx];
        }
    }

    if (gc < 4) {
        int cell = gc * 256 + gr;
        cs += *(const vf4*)&dirc[(size_t)cell * FCH + c4 * 4];
        wsm += dirw[cell];
    } else if (gr < 4) {
        int cell = (4 + gr) * 256 + gc;
        cs += *(const vf4*)&dirc[(size_t)cell * FCH + c4 * 4];
        wsm += dirw[cell];
    }

    float s = (wsm > 0.01f) ? (1.0f / (wsm + 0.001f)) : 0.0f;
    cs *= s;

    size_t base = ((size_t)gr * 256 + gc) * FCH + c4 * 4;
    #pragma unroll
    for (int b = 0; b < 8; ++b) {
        __builtin_nontemporal_store(cs, (vf4*)&out[(size_t)b * (256 * 256 * FCH) + base]);
    }
}

extern "C" void kernel_launch(void* const* d_in, const int* in_sizes, int n_in,
                              void* d_out, int out_size, void* d_ws, size_t ws_size,
                              hipStream_t stream) {
    const float*  f_map  = (const float*)d_in[0];
    const float2* uv_map = (const float2*)d_in[1];
    const float*  mask   = (const float*)d_in[2];
    float* out = (float*)d_out;
    char*  wsb = (char*)d_ws;

    const size_t STRIP_BYTES = 2048 * 16 * 4 + 2048 * 4;       // dirc + dirw
    int nrepl = 8;
    while (nrepl > 1 &&
           (size_t)nrepl * NCELL * 36 + STRIP_BYTES > ws_size) nrepl >>= 1;
    int l2n = (nrepl == 8) ? 3 : (nrepl == 4) ? 2 : (nrepl == 2) ? 1 : 0;
    int shift = 3 - l2n;                    // rep = xcc >> shift  (0..nrepl-1)

    size_t halo_bytes = (size_t)nrepl * NCELL * 32;
    size_t hcnt_bytes = (size_t)nrepl * NCELL * 4;
    __half2* halo = (__half2*)wsb;
    float*   hcnt = (float*)(wsb + halo_bytes);
    float*   dirc = (float*)(wsb + halo_bytes + hcnt_bytes);
    float*   dirw = (float*)(wsb + halo_bytes + hcnt_bytes + 2048 * 16 * 4);

    (void)hipMemsetAsync(wsb, 0, halo_bytes + hcnt_bytes + STRIP_BYTES, stream);

    splat_kernel<<<(NPIX * 8) / 256, 256, 0, stream>>>(
        f_map, uv_map, mask, halo, hcnt, dirc, dirw, shift);
    finalize_kernel<<<1024, 256, 0, stream>>>(halo, hcnt, dirc, dirw, nrepl, out);
}

// Round 24
// 61.271 us; speedup vs baseline: 1.7162x; 1.1651x over previous
//
#include <hip/hip_runtime.h>
#include <hip/hip_fp16.h>

#define TEX_H 256
#define TEX_W 256
#define FCH 16
#define NPIX (8 * 256 * 256)
#define NCELL (256 * 256)

#define SQRT2_F 1.41421356237f
// Interior weights (grid anchored at u-2 => du,dv exactly in {0,1,2};
// d=2 slots fail w>0.1, leaving the 3x3 with constant weights):
#define W_EDGE   0.24311673443f   // exp(-sqrt(2))
#define W_DIAG   0.13533528324f   // exp(-2)

typedef float vf4 __attribute__((ext_vector_type(4)));

// ws layout (bytes): halo payload fp16 (verified absmax 0.0078 < 0.032 in
// r15/r18/r23); boundary strips exact fp32.
//  halo_h [NCELL][16] __half   @ 0          (2,097,152 B)
//  halo_n [NCELL]     float    @ 2,097,152  (  262,144 B)
//  dir_c  [2048][16]  float    @ 2,359,296  (  131,072 B)
//  dir_w  [2048]      float    @ 2,490,368  (    8,192 B)
#define HALO_H_OFF 0
#define HALO_N_OFF (NCELL * 16 * 2)
#define DIR_C_OFF  (HALO_N_OFF + NCELL * 4)
#define DIR_W_OFF  (DIR_C_OFF + 2048 * 16 * 4)
#define ZERO_BYTES (DIR_W_OFF + 2048 * 4)

// ---- splat (r15, best measured: 44.6us — the scattered-RMW wall, confirmed
// across 10 structural variants). 8 lanes/pixel; lane l owns channel pair
// (2l,2l+1); one packed fp16 atomic per lane + count on lane 0. Boundary
// pixels (u<2 or v<2, ~0.8%): exact fp32 reference path into edge strips. ----
__global__ __launch_bounds__(256) void splat_kernel(
    const float*  __restrict__ f_map,
    const float2* __restrict__ uv_map,
    const float*  __restrict__ mask,
    char* __restrict__ wsb)
{
    __half2* halo = (__half2*)(wsb + HALO_H_OFF);
    float*   hcnt = (float*)  (wsb + HALO_N_OFF);
    float*   dirc = (float*)  (wsb + DIR_C_OFF);
    float*   dirw = (float*)  (wsb + DIR_W_OFF);

    int tid = blockIdx.x * 256 + threadIdx.x;
    int pix = tid >> 3;
    int l   = tid & 7;

    if (mask[pix] == 0.0f) return;

    float2 uv = uv_map[pix];
    float u = uv.x * 256.0f;
    float v = uv.y * 256.0f;

    if (u >= 2.0f && v >= 2.0f) {
        int cell = ((int)v) * 256 + (int)u;          // uv<1 => indices <=255
        float2 fp = ((const float2*)f_map)[(size_t)pix * 8 + l]; // ch 2l,2l+1
        __half2 h = __floats2half2_rn(fp.x, fp.y);
        unsafeAtomicAdd(&halo[(size_t)cell * 8 + l], h);
        if (l == 0) unsafeAtomicAdd(&hcnt[cell], 1.0f);
    } else {
        // Exact reference path; passing slots have ui<4 (u<2) or vi<4 (v<2).
        float fa = f_map[(size_t)pix * FCH + l];
        float fb = f_map[(size_t)pix * FCH + l + 8];
        float us = fmaxf(u - 2.0f, 0.0f);
        float vs = fmaxf(v - 2.0f, 0.0f);
        #pragma unroll
        for (int kv = 0; kv < 4; ++kv) {
            float vg = vs + (float)kv;
            int vi = (int)vg;
            float dvf = fabsf(vg - v);
            #pragma unroll
            for (int ku = 0; ku < 4; ++ku) {
                float ug = us + (float)ku;
                int ui = (int)ug;
                float duf = fabsf(ug - u);
                float w = expf(-sqrtf(duf * duf + dvf * dvf) * SQRT2_F);
                if (w > 0.1f && vi < TEX_H && ui < TEX_W) {
                    int cell = (ui < 4) ? (ui * 256 + vi)        // region 0 (u<2)
                                        : ((4 + vi) * 256 + ui); // region 1 (vi<4)
                    unsafeAtomicAdd(&dirc[(size_t)cell * FCH + l],     w * fa);
                    unsafeAtomicAdd(&dirc[(size_t)cell * FCH + l + 8], w * fb);
                    if (l == 0) unsafeAtomicAdd(&dirw[cell], w);
                }
            }
        }
    }
}

// ---- finalize (r15): WG = 8x8 texel tile. Stage the 10x10 halo (fp16
// payload + f32 counts) into LDS once, 3x3 const-weight conv from LDS,
// merge exact fp32 boundary strips, normalize, NT-store 8 broadcast copies. ----
__global__ __launch_bounds__(256) void finalize_kernel(
    const char* __restrict__ wsb,
    float* __restrict__ out)
{
    const __half2* halo = (const __half2*)(wsb + HALO_H_OFF);
    const float*   hcnt = (const float*)  (wsb + HALO_N_OFF);
    const float*   dirc = (const float*)  (wsb + DIR_C_OFF);
    const float*   dirw = (const float*)  (wsb + DIR_W_OFF);

    __shared__ __half2 s_h[100][8];   // 10x10 cells x 16 ch (fp16) = 3200 B
    __shared__ float   s_n[100];

    int tile = blockIdx.x;                  // 32x32 tiles of 8x8
    int r0 = (tile >> 5) << 3;
    int c0 = (tile & 31) << 3;

    int i = threadIdx.x;
    if (i < 200) {                          // 2 threads per halo cell (16B each)
        int cellIdx = i >> 1, part = i & 1;
        int hr = cellIdx / 10, hc = cellIdx - hr * 10;
        int gr = r0 + hr - 1, gc = c0 + hc - 1;
        uint4 val = make_uint4(0, 0, 0, 0);
        bool inb = (gr >= 0) & (gr < 256) & (gc >= 0) & (gc < 256);
        size_t gcell = inb ? ((size_t)gr * 256 + gc) : 0;
        if (inb)
            val = *(const uint4*)&halo[gcell * 8 + part * 4];
        *(uint4*)&s_h[cellIdx][part * 4] = val;
        if (part == 0) s_n[cellIdx] = inb ? hcnt[gcell] : 0.0f;
    }
    __syncthreads();

    int tx = threadIdx.x >> 2;              // texel in tile 0..63
    int c4 = threadIdx.x & 3;               // float4 chunk 0..3
    int lr = tx >> 3, lc = tx & 7;
    int gr = r0 + lr, gc = c0 + lc;

    vf4 cs = {0.f, 0.f, 0.f, 0.f};
    float wsm = 0.0f;

    #pragma unroll
    for (int a = 0; a < 3; ++a) {
        #pragma unroll
        for (int b = 0; b < 3; ++b) {
            float w = (a == 1 && b == 1) ? 1.0f
                    : ((a == 1 || b == 1) ? W_EDGE : W_DIAG);
            int idx = (lr + a) * 10 + (lc + b);
            float2 f0 = __half22float2(s_h[idx][c4 * 2 + 0]);
            float2 f1 = __half22float2(s_h[idx][c4 * 2 + 1]);
            cs.x += w * f0.x; cs.y += w * f0.y;
            cs.z += w * f1.x; cs.w += w * f1.y;
            wsm  += w * s_n[idx];
        }
    }

    // Boundary strip merge (exact fp32; region mapping matches splat).
    if (gc < 4) {
        int cell = gc * 256 + gr;
        cs += *(const vf4*)&dirc[(size_t)cell * FCH + c4 * 4];
        wsm += dirw[cell];
    } else if (gr < 4) {
        int cell = (4 + gr) * 256 + gc;
        cs += *(const vf4*)&dirc[(size_t)cell * FCH + c4 * 4];
        wsm += dirw[cell];
    }

    float s = (wsm > 0.01f) ? (1.0f / (wsm + 0.001f)) : 0.0f;
    cs *= s;

    size_t base = ((size_t)gr * 256 + gc) * FCH + c4 * 4;
    #pragma unroll
    for (int b = 0; b < 8; ++b) {
        __builtin_nontemporal_store(cs, (vf4*)&out[(size_t)b * (256 * 256 * FCH) + base]);
    }
}

extern "C" void kernel_launch(void* const* d_in, const int* in_sizes, int n_in,
                              void* d_out, int out_size, void* d_ws, size_t ws_size,
                              hipStream_t stream) {
    const float*  f_map  = (const float*)d_in[0];
    const float2* uv_map = (const float2*)d_in[1];
    const float*  mask   = (const float*)d_in[2];
    float* out = (float*)d_out;
    char*  wsb = (char*)d_ws;

    (void)hipMemsetAsync(wsb, 0, (size_t)ZERO_BYTES, stream);

    splat_kernel<<<(NPIX * 8) / 256, 256, 0, stream>>>(f_map, uv_map, mask, wsb);
    finalize_kernel<<<1024, 256, 0, stream>>>(wsb, out);
}